// Round 1
// baseline (199.998 us; speedup 1.0000x reference)
//
#include <hip/hip_runtime.h>
#include <hip/hip_bf16.h>

#define N_NODES 10000
#define N_EDGES 320000
#define E_TOT   330000   // + self loops
#define IN_CH   512
#define F1      512      // HEADS*HID
#define HID     128
#define HEADS   4
#define SLOTS   128      // max in-degree bound (Poisson(32)+1, max ~57 over 10k nodes)

typedef __attribute__((ext_vector_type(8))) short bf16x8;
typedef __attribute__((ext_vector_type(4))) float f32x4;

__device__ __forceinline__ float lo16(unsigned u) { return __uint_as_float(u << 16); }
__device__ __forceinline__ float hi16(unsigned u) { return __uint_as_float(u & 0xffff0000u); }
__device__ __forceinline__ unsigned short bfbits(float f) {
    __hip_bfloat16 h = __float2bfloat16(f);
    return *(unsigned short*)&h;
}

// ---- prep: x fp32->bf16 (vectorized) | W1 -> W1T bf16 (LDS-tiled transpose)
//      | zero a_src1+a_dst1+cnt as ONE contiguous 90,000-dword region
//      (replaces the separate hipMemsetAsync graph node).
__global__ void k_prep(const float* __restrict__ x, unsigned short* __restrict__ xb,
                       const float* __restrict__ w1, unsigned short* __restrict__ w1t,
                       int* __restrict__ zbase) {
    __shared__ float tile[64][65];
    int b = blockIdx.x;
    int t = threadIdx.x;
    if (b < 5000) {                       // cvt x: 1,280,000 float4s
        int idx = b * 256 + t;
        float4 v = ((const float4*)x)[idx];
        ushort4 u;
        u.x = bfbits(v.x); u.y = bfbits(v.y); u.z = bfbits(v.z); u.w = bfbits(v.w);
        ((ushort4*)xb)[idx] = u;
    } else if (b < 5064) {                // W1T: 8x8 grid of 64x64 tiles via LDS
        int bb = b - 5000;
        int bi = bb >> 3, bj = bb & 7;    // tile row (k), tile col (n)
        int r0 = t >> 6, col = t & 63;
#pragma unroll
        for (int p = 0; p < 16; ++p) {
            int row = p * 4 + r0;
            tile[row][col] = w1[(size_t)(bi * 64 + row) * 512 + bj * 64 + col];
        }
        __syncthreads();
#pragma unroll
        for (int p = 0; p < 16; ++p) {
            int row = p * 4 + r0;         // w1t[n*512+k] = w1[k*512+n]
            w1t[(size_t)(bj * 64 + row) * 512 + bi * 64 + col] = bfbits(tile[col][row]);
        }
    } else {                              // zero a_src1+a_dst1+cnt = 90,000 dwords
        int idx = (b - 5064) * 256 + t;
        if (idx < 90000) zbase[idx] = 0;
    }
}

// ---- h1b = bf16(x @ W1) + fused attention-dot partials via atomics,
//      PLUS edge-slot binning fused in as trailing blocks (independent work
//      that fills the CUs while the low-block-count GEMM runs).
// GEMM: one wave = 16 rows x 64 cols (1x4 MFMA 16x16x32 accs), register
// double-buffer on K. 625*16 = 10000 exactly -> no row clamps needed.
#define GEMM_BLKS 1250
__global__ __launch_bounds__(256) void k_gemm1(const __hip_bfloat16* __restrict__ xb,
                                               const __hip_bfloat16* __restrict__ w1t,
                                               const float* __restrict__ as_vec,
                                               const float* __restrict__ ad_vec,
                                               __hip_bfloat16* __restrict__ h1b,
                                               float* __restrict__ a_src,
                                               float* __restrict__ a_dst,
                                               const int* __restrict__ src,
                                               const int* __restrict__ dst,
                                               int* __restrict__ cnt,
                                               int* __restrict__ slots) {
    if (blockIdx.x >= GEMM_BLKS) {        // edge binning: 1290 blocks
        int e = (blockIdx.x - GEMM_BLKS) * 256 + threadIdx.x;
        if (e < E_TOT) {
            int d, s;
            if (e < N_EDGES) { d = dst[e]; s = src[e]; } else { d = e - N_EDGES; s = d; }
            int pos = atomicAdd(&cnt[d], 1);
            if (pos < SLOTS) slots[d * SLOTS + pos] = s;
        }
        return;
    }
    int wid = blockIdx.x * 4 + (threadIdx.x >> 6);   // 0..4999
    int lane = threadIdx.x & 63;
    int tm = wid >> 3, tn = wid & 7;                 // tm 0..624, tn 0..7
    int col16 = lane & 15, quad = lane >> 4;
    int klo = quad * 8;                              // A/B frag: [idx16][quad*8+j]
    int r0g = tm * 16;
    const __hip_bfloat16* ap = xb + (size_t)(r0g + col16) * IN_CH + klo;
    const __hip_bfloat16* bp = w1t + (size_t)(tn * 64 + col16) * IN_CH + klo;
    f32x4 acc[4] = {};
    bf16x8 ac = *(const bf16x8*)(ap);
    bf16x8 bc[4];
#pragma unroll
    for (int ct = 0; ct < 4; ++ct) bc[ct] = *(const bf16x8*)(bp + (size_t)(ct * 16) * IN_CH);
#pragma unroll
    for (int kt = 0; kt < IN_CH; kt += 32) {
        bf16x8 an, bn[4];
        if (kt + 32 < IN_CH) {
            an = *(const bf16x8*)(ap + kt + 32);
#pragma unroll
            for (int ct = 0; ct < 4; ++ct)
                bn[ct] = *(const bf16x8*)(bp + (size_t)(ct * 16) * IN_CH + kt + 32);
        }
#pragma unroll
        for (int ct = 0; ct < 4; ++ct)
            acc[ct] = __builtin_amdgcn_mfma_f32_16x16x32_bf16(ac, bc[ct], acc[ct], 0, 0, 0);
        if (kt + 32 < IN_CH) {
            ac = an;
#pragma unroll
            for (int ct = 0; ct < 4; ++ct) bc[ct] = bn[ct];
        }
    }
    // epilogue
    int h_w = tn >> 1;                               // head of this wave's col block
    float asv[4], adv[4];
#pragma unroll
    for (int ct = 0; ct < 4; ++ct) {
        int c = tn * 64 + ct * 16 + col16;
        asv[ct] = as_vec[c];
        adv[ct] = ad_vec[c];
    }
#pragma unroll
    for (int reg = 0; reg < 4; ++reg) {
        int row = r0g + quad * 4 + reg;              // C/D: col=lane&15, row=quad*4+reg
        float ps = 0.f, pd = 0.f;
#pragma unroll
        for (int ct = 0; ct < 4; ++ct) {
            float v = acc[ct][reg];
            ps += v * asv[ct];
            pd += v * adv[ct];
            h1b[(size_t)row * F1 + tn * 64 + ct * 16 + col16] = __float2bfloat16(v);
        }
#pragma unroll
        for (int off = 1; off <= 8; off <<= 1) {
            ps += __shfl_xor(ps, off);
            pd += __shfl_xor(pd, off);
        }
        if (col16 == 0) {
            atomicAdd(&a_src[row * HEADS + h_w], ps);
            atomicAdd(&a_dst[row * HEADS + h_w], pd);
        }
    }
}

// ---- fused softmax + aggregate + bias + ELU + layer-2 projection.
// ONE WAVE PER NODE, single pass. Depth-2 software pipeline (T14-style):
// slot indices prefetched TWO batches ahead, {a_src, h1b-row} gathers ONE
// batch ahead, so the consume phase of batch b hits data issued a full
// iteration earlier instead of draining a fresh L2/L3 gather latency.
// Arithmetic order per output element identical to the previous version.
__global__ __launch_bounds__(256) void k_aggr1(const __hip_bfloat16* __restrict__ h1b,
                                               const float* __restrict__ a_src,
                                               const float* __restrict__ a_dst,
                                               const int* __restrict__ cnt,
                                               const int* __restrict__ slots,
                                               const float* __restrict__ b1,
                                               const float* __restrict__ w2,
                                               const float* __restrict__ as2,
                                               const float* __restrict__ ad2,
                                               float* __restrict__ h2,
                                               float* __restrict__ a_src2,
                                               float* __restrict__ a_dst2) {
    int n = blockIdx.x * 4 + (threadIdx.x >> 6);
    int lane = threadIdx.x & 63;
    int h = lane >> 4;
    int cn = min(cnt[n], SLOTS);          // >= 1 (self-loop)
    const int* sl = slots + n * SLOTS;
    float adst = a_dst[n * HEADS + h];
    float dsum = 0.f;
    float acc[8] = {};
    const __hip_bfloat16* hb = h1b + lane * 8;
    int nb = (cn + 7) >> 3;

    int sB[8], sC[8] = {0, 0, 0, 0, 0, 0, 0, 0};
    float avA[8], avB[8];
    uint4 dA[8], dB[8];
    // prologue: batch0 gathers in flight + batch1 indices
#pragma unroll
    for (int j = 0; j < 8; ++j) sB[j] = sl[min(j, cn - 1)];
#pragma unroll
    for (int j = 0; j < 8; ++j) avA[j] = a_src[sB[j] * HEADS + h];
#pragma unroll
    for (int j = 0; j < 8; ++j) dA[j] = *(const uint4*)(hb + (size_t)sB[j] * F1);
#pragma unroll
    for (int j = 0; j < 8; ++j) sB[j] = sl[min(8 + j, cn - 1)];

    for (int b = 0; b < nb; ++b) {
        int i = b << 3;
        bool more = (b + 1) < nb;
        // issue slot-index loads for batch b+2 (oldest-first so the later
        // wait on sB does not drain these)
        if (b + 2 < nb) {
            int i2 = i + 16;
            if (i2 + 8 <= cn) {
                int4 u0 = *(const int4*)(sl + i2);
                int4 u1 = *(const int4*)(sl + i2 + 4);
                sC[0] = u0.x; sC[1] = u0.y; sC[2] = u0.z; sC[3] = u0.w;
                sC[4] = u1.x; sC[5] = u1.y; sC[6] = u1.z; sC[7] = u1.w;
            } else {
#pragma unroll
                for (int j = 0; j < 8; ++j) sC[j] = sl[min(i2 + j, cn - 1)];
            }
        }
        // issue gathers for batch b+1 (indices landed one iteration ago)
        if (more) {
#pragma unroll
            for (int j = 0; j < 8; ++j) avB[j] = a_src[sB[j] * HEADS + h];
#pragma unroll
            for (int j = 0; j < 8; ++j) dB[j] = *(const uint4*)(hb + (size_t)sB[j] * F1);
        }
        // consume batch b (its loads were issued one iteration ago)
        float w[8];
#pragma unroll
        for (int j = 0; j < 8; ++j) {
            float e = avA[j] + adst;
            e = fmaxf(e, 0.2f * e);       // LeakyReLU
            float ww = __expf(e);
            w[j] = (i + j < cn) ? ww : 0.f;
            dsum += w[j];
        }
#pragma unroll
        for (int j = 0; j < 8; ++j) {
            acc[0] += w[j] * lo16(dA[j].x); acc[1] += w[j] * hi16(dA[j].x);
            acc[2] += w[j] * lo16(dA[j].y); acc[3] += w[j] * hi16(dA[j].y);
            acc[4] += w[j] * lo16(dA[j].z); acc[5] += w[j] * hi16(dA[j].z);
            acc[6] += w[j] * lo16(dA[j].w); acc[7] += w[j] * hi16(dA[j].w);
        }
        if (more) {
#pragma unroll
            for (int j = 0; j < 8; ++j) { avA[j] = avB[j]; dA[j] = dB[j]; sB[j] = sC[j]; }
        }
    }
    float inv = 1.f / (dsum + 1e-16f);
    int c0 = lane * 8;
    float ps0 = 0.f, ps1 = 0.f;
#pragma unroll
    for (int j = 0; j < 8; ++j) {
        float v = acc[j] * inv + b1[c0 + j];
        v = v > 0.f ? v : __expf(v) - 1.f;            // ELU
        ps0 += v * w2[(c0 + j) * 2 + 0];
        ps1 += v * w2[(c0 + j) * 2 + 1];
    }
#pragma unroll
    for (int off = 1; off <= 32; off <<= 1) {
        ps0 += __shfl_xor(ps0, off);
        ps1 += __shfl_xor(ps1, off);
    }
    if (lane == 0) {
        h2[n * 2 + 0] = ps0;
        h2[n * 2 + 1] = ps1;
        a_src2[n] = ps0 * as2[0] + ps1 * as2[1];
        a_dst2[n] = ps0 * ad2[0] + ps1 * ad2[1];
    }
}

// ---- layer 2 softmax + aggregate (H=1, C=2), 4 nodes/wave (16 lanes each)
__global__ __launch_bounds__(256) void k_aggr2(const float* __restrict__ h2,
                                               const float* __restrict__ a_src2,
                                               const float* __restrict__ a_dst2,
                                               const int* __restrict__ cnt,
                                               const int* __restrict__ slots,
                                               const float* __restrict__ b2,
                                               float* __restrict__ out) {
    int lane = threadIdx.x & 63;
    int sub = lane >> 4, slot = lane & 15;
    int n = blockIdx.x * 16 + (threadIdx.x >> 6) * 4 + sub;
    int cn = min(cnt[n], SLOTS);
    const int* sl = slots + n * SLOTS;
    float adst = a_dst2[n];
    float dsum = 0.f, acc0 = 0.f, acc1 = 0.f;
    for (int i = slot; i < cn; i += 16) {
        int s = sl[i];
        float e = a_src2[s] + adst;
        e = fmaxf(e, 0.2f * e);
        float w = __expf(e);
        dsum += w;
        acc0 += w * h2[s * 2 + 0];
        acc1 += w * h2[s * 2 + 1];
    }
#pragma unroll
    for (int off = 1; off <= 8; off <<= 1) {
        dsum += __shfl_xor(dsum, off);
        acc0 += __shfl_xor(acc0, off);
        acc1 += __shfl_xor(acc1, off);
    }
    if (slot == 0) {
        float inv = 1.f / (dsum + 1e-16f);
        out[n * 2 + 0] = acc0 * inv + b2[0];
        out[n * 2 + 1] = acc1 * inv + b2[1];
    }
}

extern "C" void kernel_launch(void* const* d_in, const int* in_sizes, int n_in,
                              void* d_out, int out_size, void* d_ws, size_t ws_size,
                              hipStream_t stream) {
    const float* x   = (const float*)d_in[0];
    const int*   ei  = (const int*)d_in[1];
    const float* W1  = (const float*)d_in[2];
    const float* as1 = (const float*)d_in[3];
    const float* ad1 = (const float*)d_in[4];
    const float* b1  = (const float*)d_in[5];
    const float* W2  = (const float*)d_in[6];
    const float* as2 = (const float*)d_in[7];
    const float* ad2 = (const float*)d_in[8];
    const float* b2  = (const float*)d_in[9];

    char* ws = (char*)d_ws;
    __hip_bfloat16* h1b = (__hip_bfloat16*)(ws);                // 10,240,000 B
    __hip_bfloat16* xb  = (__hip_bfloat16*)(ws + 10240000);     // 10,240,000 B
    __hip_bfloat16* w1t = (__hip_bfloat16*)(ws + 20480000);     //    524,288 B
    const size_t S = 21004288;
    // a_src1/a_dst1/cnt contiguous -> zeroed as one 90,000-dword region in prep
    float* a_src1 = (float*)(ws + S);             //   160,000
    float* a_dst1 = (float*)(ws + S + 160000);    //   160,000
    int*   cnt    = (int*)(ws + S + 320000);      //    40,000
    int*   slots  = (int*)(ws + S + 360000);      // 5,120,000 (10000*128*4)
    float* h2     = (float*)(ws + S + 5480000);   //    80,000
    float* a_src2 = (float*)(ws + S + 5560000);   //    40,000
    float* a_dst2 = (float*)(ws + S + 5600000);   //    40,000

    const int* srcArr = ei;
    const int* dstArr = ei + N_EDGES;

    k_prep<<<5064 + 352, 256, 0, stream>>>(x, (unsigned short*)xb, W1,
                                           (unsigned short*)w1t, (int*)a_src1);
    k_gemm1<<<GEMM_BLKS + 1290, 256, 0, stream>>>(xb, w1t, as1, ad1, h1b,
                                                  a_src1, a_dst1,
                                                  srcArr, dstArr, cnt, slots);
    k_aggr1<<<N_NODES / 4, 256, 0, stream>>>(h1b, a_src1, a_dst1, cnt, slots, b1,
                                             W2, as2, ad2, h2, a_src2, a_dst2);
    k_aggr2<<<N_NODES / 16, 256, 0, stream>>>(h2, a_src2, a_dst2, cnt, slots, b2,
                                              (float*)d_out);
}

// Round 2
// 184.425 us; speedup vs baseline: 1.0844x; 1.0844x over previous
//
#include <hip/hip_runtime.h>
#include <hip/hip_bf16.h>

#define N_NODES 10000
#define N_EDGES 320000
#define E_TOT   330000   // + self loops
#define IN_CH   512
#define F1      512      // HEADS*HID
#define HID     128
#define HEADS   4
#define SLOTS   128      // max in-degree bound (Poisson(32)+1, max ~57 over 10k nodes)

typedef __attribute__((ext_vector_type(8))) short bf16x8;
typedef __attribute__((ext_vector_type(4))) float f32x4;

__device__ __forceinline__ float lo16(unsigned u) { return __uint_as_float(u << 16); }
__device__ __forceinline__ float hi16(unsigned u) { return __uint_as_float(u & 0xffff0000u); }
__device__ __forceinline__ unsigned short bfbits(float f) {
    __hip_bfloat16 h = __float2bfloat16(f);
    return *(unsigned short*)&h;
}

__device__ __forceinline__ void gload_lds16(const void* g, void* l) {
    __builtin_amdgcn_global_load_lds(
        (const __attribute__((address_space(1))) unsigned int*)g,
        (__attribute__((address_space(3))) unsigned int*)l, 16, 0, 0);
}

// ---- prep: x fp32->bf16 | W1 -> W1T bf16 (LDS transpose) | zero a_src1+a_dst1
//      | edge binning into fixed-slot CSR (cnt pre-zeroed by the 40KB memset
//      node, stream-ordered before this kernel — round-0-proven placement).
__global__ void k_prep(const float* __restrict__ x, unsigned short* __restrict__ xb,
                       const float* __restrict__ w1, unsigned short* __restrict__ w1t,
                       int* __restrict__ zbase,
                       const int* __restrict__ src, const int* __restrict__ dst,
                       int* __restrict__ cnt, int* __restrict__ slots) {
    __shared__ float tile[64][65];
    int b = blockIdx.x;
    int t = threadIdx.x;
    if (b < 5000) {                       // cvt x: 1,280,000 float4s
        int idx = b * 256 + t;
        float4 v = ((const float4*)x)[idx];
        ushort4 u;
        u.x = bfbits(v.x); u.y = bfbits(v.y); u.z = bfbits(v.z); u.w = bfbits(v.w);
        ((ushort4*)xb)[idx] = u;
    } else if (b < 5064) {                // W1T: 8x8 grid of 64x64 tiles via LDS
        int bb = b - 5000;
        int bi = bb >> 3, bj = bb & 7;
        int r0 = t >> 6, col = t & 63;
#pragma unroll
        for (int p = 0; p < 16; ++p) {
            int row = p * 4 + r0;
            tile[row][col] = w1[(size_t)(bi * 64 + row) * 512 + bj * 64 + col];
        }
        __syncthreads();
#pragma unroll
        for (int p = 0; p < 16; ++p) {
            int row = p * 4 + r0;         // w1t[n*512+k] = w1[k*512+n]
            w1t[(size_t)(bj * 64 + row) * 512 + bi * 64 + col] = bfbits(tile[col][row]);
        }
    } else if (b < 5377) {                // zero a_src1+a_dst1 = 80,000 dwords
        int idx = (b - 5064) * 256 + t;
        if (idx < 80000) zbase[idx] = 0;
    } else {                              // binning: blocks 5377..6666
        int e = (b - 5377) * 256 + t;
        if (e < E_TOT) {
            int d, s;
            if (e < N_EDGES) { d = dst[e]; s = src[e]; } else { d = e - N_EDGES; s = d; }
            int pos = atomicAdd(&cnt[d], 1);
            if (pos < SLOTS) slots[d * SLOTS + pos] = s;
        }
    }
}

// ---- h1b = bf16(x @ W1), LDS-staged 128x128 tile, BK=64, double-buffered
//      global_load_lds (coalesced 16B, every fetched byte used once) +
//      T2 XOR-swizzled ds_read_b128 (swizzle applied on the GLOBAL source
//      chunk since gload_lds writes linearly — both-sides-or-neither).
//      N-tile = 128 cols = exactly one head -> attention-dot epilogue
//      reduces over 16 col lanes and atomicAdds once per row per wave.
__device__ __forceinline__ void gemm_step(const __hip_bfloat16* A, const __hip_bfloat16* B,
                                          int wr, int wc, int col16, int quad,
                                          f32x4 acc[4][4]) {
#pragma unroll
    for (int kk = 0; kk < 2; ++kk) {
        bf16x8 af[4], bf[4];
#pragma unroll
        for (int m = 0; m < 4; ++m) {
            int r = wr * 64 + m * 16 + col16;
            af[m] = *(const bf16x8*)((const char*)A + r * 128 +
                                     ((kk * 64 + quad * 16) ^ ((r & 7) << 4)));
        }
#pragma unroll
        for (int c = 0; c < 4; ++c) {
            int r = wc * 64 + c * 16 + col16;
            bf[c] = *(const bf16x8*)((const char*)B + r * 128 +
                                     ((kk * 64 + quad * 16) ^ ((r & 7) << 4)));
        }
#pragma unroll
        for (int m = 0; m < 4; ++m)
#pragma unroll
            for (int c = 0; c < 4; ++c)
                acc[m][c] = __builtin_amdgcn_mfma_f32_16x16x32_bf16(af[m], bf[c], acc[m][c], 0, 0, 0);
    }
}

__global__ __launch_bounds__(256) void k_gemm1(const __hip_bfloat16* __restrict__ xb,
                                               const __hip_bfloat16* __restrict__ w1t,
                                               const float* __restrict__ as_vec,
                                               const float* __restrict__ ad_vec,
                                               __hip_bfloat16* __restrict__ h1b,
                                               float* __restrict__ a_src,
                                               float* __restrict__ a_dst) {
    __shared__ __align__(16) __hip_bfloat16 lsA[2][128 * 64];   // 2 x 16 KB
    __shared__ __align__(16) __hip_bfloat16 lsB[2][128 * 64];   // 2 x 16 KB
    int nt = blockIdx.x & 3;              // head / N-tile (128 cols)
    int mt = blockIdx.x >> 2;             // 0..78
    int row0 = mt * 128;
    int t = threadIdx.x;
    int lane = t & 63;
    int wid = t >> 6;
    int wr = wid >> 1, wc = wid & 1;      // wave quadrant: 64x64
    int col16 = lane & 15, quad = lane >> 4;

    // staging: chunk ci = p*256+t covers lds bytes [ci*16, +16); data row =
    // ci>>3, dest chunk ch = ci&7; source chunk pre-swizzled: sch = ch^(row&7)
    const __hip_bfloat16* ga[4];
    const __hip_bfloat16* gb[4];
    unsigned loff[4];
#pragma unroll
    for (int p = 0; p < 4; ++p) {
        int ci = p * 256 + t;
        int row = ci >> 3, ch = ci & 7;
        int sch = ch ^ (row & 7);
        ga[p] = xb + (size_t)min(row0 + row, N_NODES - 1) * IN_CH + sch * 8;
        gb[p] = w1t + (size_t)(nt * 128 + row) * IN_CH + sch * 8;
        loff[p] = ci * 16;
    }

    f32x4 acc[4][4] = {};

#pragma unroll
    for (int p = 0; p < 4; ++p) gload_lds16(ga[p], (char*)lsA[0] + loff[p]);
#pragma unroll
    for (int p = 0; p < 4; ++p) gload_lds16(gb[p], (char*)lsB[0] + loff[p]);
    __syncthreads();                      // drains vmcnt before barrier

#pragma unroll 1
    for (int s = 0; s < 7; ++s) {
        int nb = (s + 1) & 1, kt = (s + 1) * 64;
#pragma unroll
        for (int p = 0; p < 4; ++p) gload_lds16(ga[p] + kt, (char*)lsA[nb] + loff[p]);
#pragma unroll
        for (int p = 0; p < 4; ++p) gload_lds16(gb[p] + kt, (char*)lsB[nb] + loff[p]);
        gemm_step(lsA[s & 1], lsB[s & 1], wr, wc, col16, quad, acc);
        __syncthreads();
    }
    gemm_step(lsA[1], lsB[1], wr, wc, col16, quad, acc);

    // epilogue: store h1b + fused attention dots (head = nt)
    float asv[4], adv[4];
#pragma unroll
    for (int c = 0; c < 4; ++c) {
        int col = nt * 128 + wc * 64 + c * 16 + col16;
        asv[c] = as_vec[col];
        adv[c] = ad_vec[col];
    }
#pragma unroll
    for (int m = 0; m < 4; ++m) {
#pragma unroll
        for (int reg = 0; reg < 4; ++reg) {
            int row = row0 + wr * 64 + m * 16 + quad * 4 + reg;  // C/D: col=lane&15, row=quad*4+reg
            bool ok = row < N_NODES;
            float ps = 0.f, pd = 0.f;
#pragma unroll
            for (int c = 0; c < 4; ++c) {
                float v = acc[m][c][reg];
                ps += v * asv[c];
                pd += v * adv[c];
                if (ok) h1b[(size_t)row * F1 + nt * 128 + wc * 64 + c * 16 + col16] =
                            __float2bfloat16(v);
            }
#pragma unroll
            for (int off = 1; off <= 8; off <<= 1) {
                ps += __shfl_xor(ps, off);
                pd += __shfl_xor(pd, off);
            }
            if (col16 == 0 && ok) {
                atomicAdd(&a_src[row * HEADS + nt], ps);
                atomicAdd(&a_dst[row * HEADS + nt], pd);
            }
        }
    }
}

// ---- fused softmax + aggregate + bias + ELU + layer-2 projection.
// ONE WAVE PER NODE, single pass, depth-2 software pipeline (unchanged).
__global__ __launch_bounds__(256) void k_aggr1(const __hip_bfloat16* __restrict__ h1b,
                                               const float* __restrict__ a_src,
                                               const float* __restrict__ a_dst,
                                               const int* __restrict__ cnt,
                                               const int* __restrict__ slots,
                                               const float* __restrict__ b1,
                                               const float* __restrict__ w2,
                                               const float* __restrict__ as2,
                                               const float* __restrict__ ad2,
                                               float* __restrict__ h2,
                                               float* __restrict__ a_src2,
                                               float* __restrict__ a_dst2) {
    int n = blockIdx.x * 4 + (threadIdx.x >> 6);
    int lane = threadIdx.x & 63;
    int h = lane >> 4;
    int cn = min(cnt[n], SLOTS);          // >= 1 (self-loop)
    const int* sl = slots + n * SLOTS;
    float adst = a_dst[n * HEADS + h];
    float dsum = 0.f;
    float acc[8] = {};
    const __hip_bfloat16* hb = h1b + lane * 8;
    int nb = (cn + 7) >> 3;

    int sB[8], sC[8] = {0, 0, 0, 0, 0, 0, 0, 0};
    float avA[8], avB[8];
    uint4 dA[8], dB[8];
#pragma unroll
    for (int j = 0; j < 8; ++j) sB[j] = sl[min(j, cn - 1)];
#pragma unroll
    for (int j = 0; j < 8; ++j) avA[j] = a_src[sB[j] * HEADS + h];
#pragma unroll
    for (int j = 0; j < 8; ++j) dA[j] = *(const uint4*)(hb + (size_t)sB[j] * F1);
#pragma unroll
    for (int j = 0; j < 8; ++j) sB[j] = sl[min(8 + j, cn - 1)];

    for (int b = 0; b < nb; ++b) {
        int i = b << 3;
        bool more = (b + 1) < nb;
        if (b + 2 < nb) {
            int i2 = i + 16;
            if (i2 + 8 <= cn) {
                int4 u0 = *(const int4*)(sl + i2);
                int4 u1 = *(const int4*)(sl + i2 + 4);
                sC[0] = u0.x; sC[1] = u0.y; sC[2] = u0.z; sC[3] = u0.w;
                sC[4] = u1.x; sC[5] = u1.y; sC[6] = u1.z; sC[7] = u1.w;
            } else {
#pragma unroll
                for (int j = 0; j < 8; ++j) sC[j] = sl[min(i2 + j, cn - 1)];
            }
        }
        if (more) {
#pragma unroll
            for (int j = 0; j < 8; ++j) avB[j] = a_src[sB[j] * HEADS + h];
#pragma unroll
            for (int j = 0; j < 8; ++j) dB[j] = *(const uint4*)(hb + (size_t)sB[j] * F1);
        }
        float w[8];
#pragma unroll
        for (int j = 0; j < 8; ++j) {
            float e = avA[j] + adst;
            e = fmaxf(e, 0.2f * e);       // LeakyReLU
            float ww = __expf(e);
            w[j] = (i + j < cn) ? ww : 0.f;
            dsum += w[j];
        }
#pragma unroll
        for (int j = 0; j < 8; ++j) {
            acc[0] += w[j] * lo16(dA[j].x); acc[1] += w[j] * hi16(dA[j].x);
            acc[2] += w[j] * lo16(dA[j].y); acc[3] += w[j] * hi16(dA[j].y);
            acc[4] += w[j] * lo16(dA[j].z); acc[5] += w[j] * hi16(dA[j].z);
            acc[6] += w[j] * lo16(dA[j].w); acc[7] += w[j] * hi16(dA[j].w);
        }
        if (more) {
#pragma unroll
            for (int j = 0; j < 8; ++j) { avA[j] = avB[j]; dA[j] = dB[j]; sB[j] = sC[j]; }
        }
    }
    float inv = 1.f / (dsum + 1e-16f);
    int c0 = lane * 8;
    float ps0 = 0.f, ps1 = 0.f;
#pragma unroll
    for (int j = 0; j < 8; ++j) {
        float v = acc[j] * inv + b1[c0 + j];
        v = v > 0.f ? v : __expf(v) - 1.f;            // ELU
        ps0 += v * w2[(c0 + j) * 2 + 0];
        ps1 += v * w2[(c0 + j) * 2 + 1];
    }
#pragma unroll
    for (int off = 1; off <= 32; off <<= 1) {
        ps0 += __shfl_xor(ps0, off);
        ps1 += __shfl_xor(ps1, off);
    }
    if (lane == 0) {
        h2[n * 2 + 0] = ps0;
        h2[n * 2 + 1] = ps1;
        a_src2[n] = ps0 * as2[0] + ps1 * as2[1];
        a_dst2[n] = ps0 * ad2[0] + ps1 * ad2[1];
    }
}

// ---- layer 2 softmax + aggregate (H=1, C=2), 4 nodes/wave (16 lanes each)
__global__ __launch_bounds__(256) void k_aggr2(const float* __restrict__ h2,
                                               const float* __restrict__ a_src2,
                                               const float* __restrict__ a_dst2,
                                               const int* __restrict__ cnt,
                                               const int* __restrict__ slots,
                                               const float* __restrict__ b2,
                                               float* __restrict__ out) {
    int lane = threadIdx.x & 63;
    int sub = lane >> 4, slot = lane & 15;
    int n = blockIdx.x * 16 + (threadIdx.x >> 6) * 4 + sub;
    int cn = min(cnt[n], SLOTS);
    const int* sl = slots + n * SLOTS;
    float adst = a_dst2[n];
    float dsum = 0.f, acc0 = 0.f, acc1 = 0.f;
    for (int i = slot; i < cn; i += 16) {
        int s = sl[i];
        float e = a_src2[s] + adst;
        e = fmaxf(e, 0.2f * e);
        float w = __expf(e);
        dsum += w;
        acc0 += w * h2[s * 2 + 0];
        acc1 += w * h2[s * 2 + 1];
    }
#pragma unroll
    for (int off = 1; off <= 8; off <<= 1) {
        dsum += __shfl_xor(dsum, off);
        acc0 += __shfl_xor(acc0, off);
        acc1 += __shfl_xor(acc1, off);
    }
    if (slot == 0) {
        float inv = 1.f / (dsum + 1e-16f);
        out[n * 2 + 0] = acc0 * inv + b2[0];
        out[n * 2 + 1] = acc1 * inv + b2[1];
    }
}

extern "C" void kernel_launch(void* const* d_in, const int* in_sizes, int n_in,
                              void* d_out, int out_size, void* d_ws, size_t ws_size,
                              hipStream_t stream) {
    const float* x   = (const float*)d_in[0];
    const int*   ei  = (const int*)d_in[1];
    const float* W1  = (const float*)d_in[2];
    const float* as1 = (const float*)d_in[3];
    const float* ad1 = (const float*)d_in[4];
    const float* b1  = (const float*)d_in[5];
    const float* W2  = (const float*)d_in[6];
    const float* as2 = (const float*)d_in[7];
    const float* ad2 = (const float*)d_in[8];
    const float* b2  = (const float*)d_in[9];

    char* ws = (char*)d_ws;
    __hip_bfloat16* h1b = (__hip_bfloat16*)(ws);                // 10,240,000 B
    __hip_bfloat16* xb  = (__hip_bfloat16*)(ws + 10240000);     // 10,240,000 B
    __hip_bfloat16* w1t = (__hip_bfloat16*)(ws + 20480000);     //    524,288 B
    const size_t S = 21004288;
    float* a_src1 = (float*)(ws + S);             //   160,000
    float* a_dst1 = (float*)(ws + S + 160000);    //   160,000
    int*   cnt    = (int*)(ws + S + 320000);      //    40,000
    int*   slots  = (int*)(ws + S + 360000);      // 5,120,000 (10000*128*4)
    float* h2     = (float*)(ws + S + 5480000);   //    80,000
    float* a_src2 = (float*)(ws + S + 5560000);   //    40,000
    float* a_dst2 = (float*)(ws + S + 5600000);   //    40,000

    const int* srcArr = ei;
    const int* dstArr = ei + N_EDGES;

    hipMemsetAsync(cnt, 0, N_NODES * sizeof(int), stream);
    k_prep<<<5377 + 1290, 256, 0, stream>>>(x, (unsigned short*)xb, W1,
                                            (unsigned short*)w1t, (int*)a_src1,
                                            srcArr, dstArr, cnt, slots);
    k_gemm1<<<316, 256, 0, stream>>>(xb, w1t, as1, ad1, h1b, a_src1, a_dst1);
    k_aggr1<<<N_NODES / 4, 256, 0, stream>>>(h1b, a_src1, a_dst1, cnt, slots, b1,
                                             W2, as2, ad2, h2, a_src2, a_dst2);
    k_aggr2<<<N_NODES / 16, 256, 0, stream>>>(h2, a_src2, a_dst2, cnt, slots, b2,
                                              (float*)d_out);
}